// Round 1
// baseline (589.785 us; speedup 1.0000x reference)
//
#include <hip/hip_runtime.h>
#include <float.h>
#include <math.h>
#include <stdint.h>

#define T_ 1024
#define D_ 1024
#define H_ 16
#define HD_ 64
#define E_ 8
#define F_ 2560
#define D3_ 3072
#define F2_ 5120

// ---- workspace layout (float offsets) ----
#define WS_H    0u         // 1M   LN1 out; later reused as SACC (split-K accum)
#define WS_QKV  1048576u   // 3M   qkv (T,3D)
#define WS_ATTN 4194304u   // 1M   attention out (T,D)
#define WS_X2   5242880u   // 1M   x + attn proj (T,D)
#define WS_H2   6291456u   // 1M   LN2 out
#define WS_A    7340032u   // 2.62M gated activation (T,F)
#define WS_GW   9961472u
#define WS_GI   9962496u
#define WS_OFFS 9963520u
#define WS_PERM 9963536u

typedef short short8 __attribute__((ext_vector_type(8)));
typedef short short4v __attribute__((ext_vector_type(4)));
typedef __bf16 bf16x8 __attribute__((ext_vector_type(8)));
typedef float floatx4 __attribute__((ext_vector_type(4)));

union FragU { short8 s; bf16x8 b; };

__device__ __forceinline__ short f2bf(float f) {
    union { float f; uint32_t u; } a; a.f = f;
    uint32_t r = a.u + 0x7fffu + ((a.u >> 16) & 1u);
    return (short)(r >> 16);
}

__device__ __forceinline__ void cvt16(const float4& a0, const float4& a1,
                                      const float4& a2, const float4& a3,
                                      short8& c0, short8& c1) {
    c0[0]=f2bf(a0.x); c0[1]=f2bf(a0.y); c0[2]=f2bf(a0.z); c0[3]=f2bf(a0.w);
    c0[4]=f2bf(a1.x); c0[5]=f2bf(a1.y); c0[6]=f2bf(a1.z); c0[7]=f2bf(a1.w);
    c1[0]=f2bf(a2.x); c1[1]=f2bf(a2.y); c1[2]=f2bf(a2.z); c1[3]=f2bf(a2.w);
    c1[4]=f2bf(a3.x); c1[5]=f2bf(a3.y); c1[6]=f2bf(a3.z); c1[7]=f2bf(a3.w);
}

// ===================== MFMA GEMM cores (register-pipelined) =====================
// Tile: BM=128, BN=64, BK=32. 256 thr = 4 waves (2x2), wave tile 64x32.
#define GEMM_IDS \
    const int tid  = threadIdx.x;                 \
    const int a_m  = tid >> 1;                    \
    const int a_kh = (tid & 1) * 16;              \
    const int lane = tid & 63, wave = tid >> 6;   \
    const int wm = wave & 1,  wn = wave >> 1;     \
    const int quad = lane >> 4, lm = lane & 15;

__global__ __launch_bounds__(256) void gemm_mfma_full(
    const float* __restrict__ A, int lda,
    const float* __restrict__ B, int ldb,
    const float* __restrict__ bias,
    float* __restrict__ C, int ldc, int K)
{
    __shared__ __align__(16) short As[4*128*8];
    __shared__ __align__(16) short Bs[64*40];
    const int row0 = blockIdx.y * 128, col0 = blockIdx.x * 64;
    GEMM_IDS
    const int b_n = tid >> 2, b_kc = tid & 3;
    floatx4 acc[4][2];
    #pragma unroll
    for (int i=0;i<4;i++)
        #pragma unroll
        for (int j=0;j<2;j++) acc[i][j] = (floatx4){0.f,0.f,0.f,0.f};

    const float* apx = A + (size_t)(row0 + a_m) * lda + a_kh;
    const float* bpx = B + (size_t)(b_kc*8) * ldb + col0 + b_n;
    const int kcA = (tid & 1) * 2;

    float4 a0, a1, a2, a3; float bvv[8];
    // preload k=0
    a0 = *(const float4*)(apx);     a1 = *(const float4*)(apx + 4);
    a2 = *(const float4*)(apx + 8); a3 = *(const float4*)(apx + 12);
    #pragma unroll
    for (int j=0;j<8;j++) bvv[j] = bpx[(size_t)j*ldb];

    for (int k0 = 0; k0 < K; k0 += 32) {
        __syncthreads();
        short8 c0, c1, cb;
        cvt16(a0,a1,a2,a3,c0,c1);
        #pragma unroll
        for (int j=0;j<8;j++) cb[j] = f2bf(bvv[j]);
        *(short8*)&As[((kcA  )*128 + a_m)*8] = c0;
        *(short8*)&As[((kcA+1)*128 + a_m)*8] = c1;
        *(short8*)&Bs[b_n*40 + b_kc*8] = cb;
        __syncthreads();
        if (k0 + 32 < K) {   // prefetch next tile (overlaps MFMA below)
            const float* ap2 = apx + k0 + 32;
            a0 = *(const float4*)(ap2);     a1 = *(const float4*)(ap2 + 4);
            a2 = *(const float4*)(ap2 + 8); a3 = *(const float4*)(ap2 + 12);
            const float* bp2 = bpx + (size_t)(k0+32) * ldb;
            #pragma unroll
            for (int j=0;j<8;j++) bvv[j] = bp2[(size_t)j*ldb];
        }
        FragU fa[4], fb[2];
        #pragma unroll
        for (int i=0;i<4;i++) fa[i].s = *(short8*)&As[(quad*128 + wm*64 + i*16 + lm)*8];
        #pragma unroll
        for (int j=0;j<2;j++) fb[j].s = *(short8*)&Bs[(wn*32 + j*16 + lm)*40 + quad*8];
        #pragma unroll
        for (int i=0;i<4;i++)
            #pragma unroll
            for (int j=0;j<2;j++)
                acc[i][j] = __builtin_amdgcn_mfma_f32_16x16x32_bf16(fa[i].b, fb[j].b, acc[i][j], 0,0,0);
    }
    #pragma unroll
    for (int i=0;i<4;i++)
        #pragma unroll
        for (int j=0;j<2;j++) {
            int col = col0 + wn*32 + j*16 + lm;
            float bb = bias ? bias[col] : 0.f;
            #pragma unroll
            for (int r=0;r<4;r++) {
                int row = row0 + wm*64 + i*16 + quad*4 + r;
                C[(size_t)row*ldc + col] = acc[i][j][r] + bb;
            }
        }
}

// split-K accumulating GEMM (optionally token-routed): Cacc += A@B
// blockIdx.z: sk = z % nsk, e = z / nsk.
__global__ __launch_bounds__(256) void gemm_mfma_acc(
    const float* __restrict__ A, int lda,
    const float* __restrict__ B, int ldb, long sB,
    const int* __restrict__ offs, const int* __restrict__ perm,
    float* __restrict__ Cacc, int ldc, int K, int nsk)
{
    const int sk = blockIdx.z % nsk;
    const int e  = blockIdx.z / nsk;
    int off = 0, Ne = T_;
    if (offs) { off = offs[e]; Ne = offs[e+1] - off; }
    const int row0 = blockIdx.y * 128;
    if (row0 >= Ne) return;
    const int col0 = blockIdx.x * 64;
    B += (long)e * sB;

    __shared__ __align__(16) short As[4*128*8];
    __shared__ __align__(16) short Bs[64*40];
    __shared__ int toks[128];
    GEMM_IDS
    const int b_n = tid >> 2, b_kc = tid & 3;
    if (tid < 128) {
        int r = row0 + tid;
        toks[tid] = offs ? ((r < Ne) ? perm[off + r] : -1) : r;
    }
    __syncthreads();

    floatx4 acc[4][2];
    #pragma unroll
    for (int i=0;i<4;i++)
        #pragma unroll
        for (int j=0;j<2;j++) acc[i][j] = (floatx4){0.f,0.f,0.f,0.f};

    const int tokA = toks[a_m];
    const float* apx = (tokA >= 0) ? (A + (size_t)tokA * lda + a_kh) : nullptr;
    const float* bpx = B + (size_t)(b_kc*8) * ldb + col0 + b_n;
    const int kcA = (tid & 1) * 2;
    const int Kp = K / nsk;
    const int koff = sk * Kp, kend = koff + Kp;

    float4 a0, a1, a2, a3; float bvv[8];
    a0 = make_float4(0,0,0,0); a1 = a0; a2 = a0; a3 = a0;
    if (apx) {
        a0 = *(const float4*)(apx + koff);     a1 = *(const float4*)(apx + koff + 4);
        a2 = *(const float4*)(apx + koff + 8); a3 = *(const float4*)(apx + koff + 12);
    }
    {
        const float* bp2 = bpx + (size_t)koff * ldb;
        #pragma unroll
        for (int j=0;j<8;j++) bvv[j] = bp2[(size_t)j*ldb];
    }

    for (int k0 = koff; k0 < kend; k0 += 32) {
        __syncthreads();
        short8 c0, c1, cb;
        cvt16(a0,a1,a2,a3,c0,c1);
        #pragma unroll
        for (int j=0;j<8;j++) cb[j] = f2bf(bvv[j]);
        *(short8*)&As[((kcA  )*128 + a_m)*8] = c0;
        *(short8*)&As[((kcA+1)*128 + a_m)*8] = c1;
        *(short8*)&Bs[b_n*40 + b_kc*8] = cb;
        __syncthreads();
        if (k0 + 32 < kend) {
            if (apx) {
                const float* ap2 = apx + k0 + 32;
                a0 = *(const float4*)(ap2);     a1 = *(const float4*)(ap2 + 4);
                a2 = *(const float4*)(ap2 + 8); a3 = *(const float4*)(ap2 + 12);
            }
            const float* bp2 = bpx + (size_t)(k0+32) * ldb;
            #pragma unroll
            for (int j=0;j<8;j++) bvv[j] = bp2[(size_t)j*ldb];
        }
        FragU fa[4], fb[2];
        #pragma unroll
        for (int i=0;i<4;i++) fa[i].s = *(short8*)&As[(quad*128 + wm*64 + i*16 + lm)*8];
        #pragma unroll
        for (int j=0;j<2;j++) fb[j].s = *(short8*)&Bs[(wn*32 + j*16 + lm)*40 + quad*8];
        #pragma unroll
        for (int i=0;i<4;i++)
            #pragma unroll
            for (int j=0;j<2;j++)
                acc[i][j] = __builtin_amdgcn_mfma_f32_16x16x32_bf16(fa[i].b, fb[j].b, acc[i][j], 0,0,0);
    }
    #pragma unroll
    for (int i=0;i<4;i++)
        #pragma unroll
        for (int j=0;j<2;j++) {
            int col = col0 + wn*32 + j*16 + lm;
            #pragma unroll
            for (int r=0;r<4;r++) {
                int tk = toks[wm*64 + i*16 + quad*4 + r];
                if (tk >= 0) atomicAdd(&Cacc[(size_t)tk*ldc + col], acc[i][j][r]);
            }
        }
}

// MoE fc: BN=32-col pair (x1 col c, x2 col F_+c), wave tile 64x16, GLU epilogue.
__global__ __launch_bounds__(256) void moe_fc_mfma(
    const float* __restrict__ h2, const float* __restrict__ fcw,
    const float* __restrict__ fcb, const int* __restrict__ offs,
    const int* __restrict__ perm, float* __restrict__ aout)
{
    const int e = blockIdx.z;
    const int off = offs[e];
    const int Ne = offs[e+1] - off;
    const int row0 = blockIdx.y * 128;
    if (row0 >= Ne) return;
    const int col0 = blockIdx.x * 32;

    __shared__ __align__(16) short As[4*128*8];
    __shared__ __align__(16) short B1s[32*40];
    __shared__ __align__(16) short B2s[32*40];
    __shared__ int toks[128];
    GEMM_IDS
    const int n_l = tid & 31, kg = tid >> 5;   // B: col n_l, k-rows kg*4..+3
    if (tid < 128) {
        int r = row0 + tid;
        toks[tid] = (r < Ne) ? perm[off + r] : -1;
    }
    __syncthreads();

    floatx4 acc1[4], acc2[4];
    #pragma unroll
    for (int i=0;i<4;i++) {
        acc1[i] = (floatx4){0.f,0.f,0.f,0.f};
        acc2[i] = (floatx4){0.f,0.f,0.f,0.f};
    }

    const float* W = fcw + (size_t)e * D_ * F2_;
    const int tokA = toks[a_m];
    const float* apx = (tokA >= 0) ? (h2 + (size_t)tokA * D_ + a_kh) : nullptr;
    const float* bpx = W + (size_t)(kg*4) * F2_ + col0 + n_l;
    const int kcA = (tid & 1) * 2;

    float4 a0, a1, a2, a3; float b1v[4], b2v[4];
    a0 = make_float4(0,0,0,0); a1 = a0; a2 = a0; a3 = a0;
    if (apx) {
        a0 = *(const float4*)(apx);     a1 = *(const float4*)(apx + 4);
        a2 = *(const float4*)(apx + 8); a3 = *(const float4*)(apx + 12);
    }
    #pragma unroll
    for (int j=0;j<4;j++) { b1v[j] = bpx[(size_t)j*F2_]; b2v[j] = bpx[(size_t)j*F2_ + F_]; }

    for (int k0 = 0; k0 < D_; k0 += 32) {
        __syncthreads();
        short8 c0, c1;
        short4v cb1, cb2;
        cvt16(a0,a1,a2,a3,c0,c1);
        #pragma unroll
        for (int j=0;j<4;j++) { cb1[j] = f2bf(b1v[j]); cb2[j] = f2bf(b2v[j]); }
        *(short8*)&As[((kcA  )*128 + a_m)*8] = c0;
        *(short8*)&As[((kcA+1)*128 + a_m)*8] = c1;
        *(short4v*)&B1s[n_l*40 + kg*4] = cb1;
        *(short4v*)&B2s[n_l*40 + kg*4] = cb2;
        __syncthreads();
        if (k0 + 32 < D_) {
            if (apx) {
                const float* ap2 = apx + k0 + 32;
                a0 = *(const float4*)(ap2);     a1 = *(const float4*)(ap2 + 4);
                a2 = *(const float4*)(ap2 + 8); a3 = *(const float4*)(ap2 + 12);
            }
            const float* bp2 = bpx + (size_t)(k0+32) * F2_;
            #pragma unroll
            for (int j=0;j<4;j++) { b1v[j] = bp2[(size_t)j*F2_]; b2v[j] = bp2[(size_t)j*F2_ + F_]; }
        }
        FragU fa[4], fb1, fb2;
        #pragma unroll
        for (int i=0;i<4;i++) fa[i].s = *(short8*)&As[(quad*128 + wm*64 + i*16 + lm)*8];
        fb1.s = *(short8*)&B1s[(wn*16 + lm)*40 + quad*8];
        fb2.s = *(short8*)&B2s[(wn*16 + lm)*40 + quad*8];
        #pragma unroll
        for (int i=0;i<4;i++) {
            acc1[i] = __builtin_amdgcn_mfma_f32_16x16x32_bf16(fa[i].b, fb1.b, acc1[i], 0,0,0);
            acc2[i] = __builtin_amdgcn_mfma_f32_16x16x32_bf16(fa[i].b, fb2.b, acc2[i], 0,0,0);
        }
    }
    {
        int col = col0 + wn*16 + lm;
        float b1 = fcb[(size_t)e*F2_ + col];
        float b2 = fcb[(size_t)e*F2_ + F_ + col];
        #pragma unroll
        for (int i=0;i<4;i++)
            #pragma unroll
            for (int r=0;r<4;r++) {
                int tk = toks[wm*64 + i*16 + quad*4 + r];
                if (tk < 0) continue;
                float v1 = acc1[i][r] + b1;
                float v2 = acc2[i][r] + b2;
                float g = v2 * 0.5f * (1.0f + erff(v2 * 0.70710678118654752f));
                aout[(size_t)tk*F_ + col] = v1 * g;
            }
    }
}

// ===================== MFMA flash attention (round-3, unchanged) =====================
__global__ __launch_bounds__(128) void flash_attn(
    const float* __restrict__ qkv, const int* __restrict__ ids,
    float* __restrict__ attnout)
{
    const int h  = blockIdx.y;
    const int q0 = blockIdx.x * 32;
    const int tid = threadIdx.x;
    const int lane = tid & 63, w = tid >> 6;
    const int quad = lane >> 4, lm = lane & 15;

    __shared__ __align__(16) short Qs[32*72];
    __shared__ __align__(16) short Ks[64*72];
    __shared__ __align__(16) short Vt[64*72];
    __shared__ __align__(16) short Ps[2][16*72];
    __shared__ int globf[32];

    {
        int row = tid >> 2, c = (tid & 3) * 16;
        const float* qp = qkv + (size_t)(q0 + row) * D3_ + h * HD_ + c;
        float4 f0 = *(const float4*)(qp);
        float4 f1 = *(const float4*)(qp + 4);
        float4 f2 = *(const float4*)(qp + 8);
        float4 f3 = *(const float4*)(qp + 12);
        short8 s0, s1;
        cvt16(f0, f1, f2, f3, s0, s1);
        *(short8*)&Qs[row*72 + c]     = s0;
        *(short8*)&Qs[row*72 + c + 8] = s1;
    }
    if (tid < 32) {
        int id = ids[q0 + tid];
        globf[tid] = (id >= 2 && id <= 7) ? 1 : 0;
    }
    __syncthreads();

    FragU QA[2];
    #pragma unroll
    for (int s = 0; s < 2; s++)
        QA[s].s = *(short8*)&Qs[(w*16 + lm)*72 + s*32 + quad*8];

    int any = 0;
    #pragma unroll
    for (int i = 0; i < 32; i++) any |= globf[i];
    const int nt = any ? (T_/64) : ((q0 + 31) >> 6) + 1;

    int gq[4]; int qidx[4];
    #pragma unroll
    for (int r = 0; r < 4; r++) {
        int ql = w*16 + quad*4 + r;
        qidx[r] = q0 + ql;
        gq[r] = globf[ql];
    }

    float mrow[4] = {-1e30f, -1e30f, -1e30f, -1e30f};
    float lrow[4] = {0.f, 0.f, 0.f, 0.f};
    floatx4 Oacc[4];
    #pragma unroll
    for (int n = 0; n < 4; n++) Oacc[n] = (floatx4){0.f, 0.f, 0.f, 0.f};

    for (int kt = 0; kt < nt; kt++) {
        __syncthreads();
        #pragma unroll
        for (int rep = 0; rep < 2; rep++) {
            int key = (tid >> 2) + rep*32;
            int c = (tid & 3) * 16;
            const float* kp = qkv + (size_t)(kt*64 + key) * D3_ + D_ + h*HD_ + c;
            float4 f0 = *(const float4*)(kp);
            float4 f1 = *(const float4*)(kp + 4);
            float4 f2 = *(const float4*)(kp + 8);
            float4 f3 = *(const float4*)(kp + 12);
            short8 s0, s1;
            cvt16(f0, f1, f2, f3, s0, s1);
            *(short8*)&Ks[key*72 + c]     = s0;
            *(short8*)&Ks[key*72 + c + 8] = s1;
        }
        #pragma unroll
        for (int rep = 0; rep < 8; rep++) {
            int lin = tid + rep*128;
            int key = lin >> 4;
            int c = (lin & 15) * 4;
            const float* vp = qkv + (size_t)(kt*64 + key) * D3_ + 2*D_ + h*HD_ + c;
            float4 f = *(const float4*)vp;
            Vt[(c+0)*72 + key] = f2bf(f.x);
            Vt[(c+1)*72 + key] = f2bf(f.y);
            Vt[(c+2)*72 + key] = f2bf(f.z);
            Vt[(c+3)*72 + key] = f2bf(f.w);
        }
        __syncthreads();

        floatx4 Sv[4];
        #pragma unroll
        for (int n = 0; n < 4; n++) {
            Sv[n] = (floatx4){0.f, 0.f, 0.f, 0.f};
            #pragma unroll
            for (int s = 0; s < 2; s++) {
                FragU KB;
                KB.s = *(short8*)&Ks[(n*16 + lm)*72 + s*32 + quad*8];
                Sv[n] = __builtin_amdgcn_mfma_f32_16x16x32_bf16(QA[s].b, KB.b, Sv[n], 0, 0, 0);
            }
        }
        #pragma unroll
        for (int n = 0; n < 4; n++) {
            int key = kt*64 + n*16 + lm;
            #pragma unroll
            for (int r = 0; r < 4; r++) {
                float v = Sv[n][r] * 0.125f;
                if (!gq[r] && key > qidx[r]) v = -1e30f;
                Sv[n][r] = v;
            }
        }
        float mnew[4], alpha[4], tsum[4];
        #pragma unroll
        for (int r = 0; r < 4; r++) {
            float tm = fmaxf(fmaxf(Sv[0][r], Sv[1][r]), fmaxf(Sv[2][r], Sv[3][r]));
            #pragma unroll
            for (int x = 1; x < 16; x <<= 1) tm = fmaxf(tm, __shfl_xor(tm, x));
            mnew[r] = fmaxf(mrow[r], tm);
            alpha[r] = __expf(mrow[r] - mnew[r]);
            mrow[r] = mnew[r];
            tsum[r] = 0.f;
        }
        #pragma unroll
        for (int n = 0; n < 4; n++) {
            #pragma unroll
            for (int r = 0; r < 4; r++) {
                float p = __expf(Sv[n][r] - mnew[r]);
                tsum[r] += p;
                Ps[w][(quad*4 + r)*72 + n*16 + lm] = f2bf(p);
            }
        }
        #pragma unroll
        for (int r = 0; r < 4; r++) {
            #pragma unroll
            for (int x = 1; x < 16; x <<= 1) tsum[r] += __shfl_xor(tsum[r], x);
            lrow[r] = lrow[r] * alpha[r] + tsum[r];
        }
        #pragma unroll
        for (int n = 0; n < 4; n++)
            #pragma unroll
            for (int r = 0; r < 4; r++) Oacc[n][r] *= alpha[r];

        #pragma unroll
        for (int s = 0; s < 2; s++) {
            FragU PA;
            PA.s = *(short8*)&Ps[w][lm*72 + s*32 + quad*8];
            #pragma unroll
            for (int n = 0; n < 4; n++) {
                FragU VB;
                VB.s = *(short8*)&Vt[(n*16 + lm)*72 + s*32 + quad*8];
                Oacc[n] = __builtin_amdgcn_mfma_f32_16x16x32_bf16(PA.b, VB.b, Oacc[n], 0, 0, 0);
            }
        }
    }

    #pragma unroll
    for (int n = 0; n < 4; n++)
        #pragma unroll
        for (int r = 0; r < 4; r++) {
            float o = Oacc[n][r] / lrow[r];
            attnout[(size_t)qidx[r]*D_ + h*HD_ + n*16 + lm] = o;
        }
}

// ===================== epilogues =====================
__global__ __launch_bounds__(256) void ep_attn(
    const float* __restrict__ x, const float* __restrict__ sacc,
    const float* __restrict__ aob, float* __restrict__ x2)
{
    int row = blockIdx.x, tid = threadIdx.x;
    float4 xv = ((const float4*)(x + (size_t)row*D_))[tid];
    float4 sv = ((const float4*)(sacc + (size_t)row*D_))[tid];
    float4 bv = ((const float4*)aob)[tid];
    float4 o;
    o.x = xv.x + sv.x + bv.x; o.y = xv.y + sv.y + bv.y;
    o.z = xv.z + sv.z + bv.z; o.w = xv.w + sv.w + bv.w;
    ((float4*)(x2 + (size_t)row*D_))[tid] = o;
}

__global__ __launch_bounds__(256) void ep_moe(
    const float* __restrict__ x2, const float* __restrict__ sacc,
    const float* __restrict__ eob, const float* __restrict__ gw,
    const int* __restrict__ gi, float* __restrict__ out)
{
    int row = blockIdx.x, tid = threadIdx.x;
    float g = gw[row];
    int e = gi[row];
    float4 xv = ((const float4*)(x2 + (size_t)row*D_))[tid];
    float4 sv = ((const float4*)(sacc + (size_t)row*D_))[tid];
    float4 bv = ((const float4*)(eob + (size_t)e*D_))[tid];
    float4 o;
    o.x = xv.x + g*(sv.x + bv.x); o.y = xv.y + g*(sv.y + bv.y);
    o.z = xv.z + g*(sv.z + bv.z); o.w = xv.w + g*(sv.w + bv.w);
    ((float4*)(out + (size_t)row*D_))[tid] = o;
}

// ===================== small kernels =====================
__global__ __launch_bounds__(256) void ln_kernel(
    const float* __restrict__ x, const float* __restrict__ w,
    const float* __restrict__ b, float* __restrict__ out)
{
    const int row = blockIdx.x, tid = threadIdx.x;
    const int lane = tid & 63, wave = tid >> 6;
    float4 v = ((const float4*)(x + (size_t)row * D_))[tid];
    float s  = v.x + v.y + v.z + v.w;
    float sq = v.x*v.x + v.y*v.y + v.z*v.z + v.w*v.w;
    #pragma unroll
    for (int off = 32; off; off >>= 1) {
        s  += __shfl_down(s, off);
        sq += __shfl_down(sq, off);
    }
    __shared__ float rs[4], rq[4], mv[2];
    if (lane == 0) { rs[wave] = s; rq[wave] = sq; }
    __syncthreads();
    if (tid == 0) {
        float ts = rs[0]+rs[1]+rs[2]+rs[3];
        float tq = rq[0]+rq[1]+rq[2]+rq[3];
        float mean = ts * (1.0f / D_);
        float var  = tq * (1.0f / D_) - mean*mean;
        mv[0] = mean; mv[1] = rsqrtf(var + 1e-5f);
    }
    __syncthreads();
    float mean = mv[0], rstd = mv[1];
    float4 wv = ((const float4*)w)[tid];
    float4 bv = ((const float4*)b)[tid];
    float4 o;
    o.x = (v.x-mean)*rstd*wv.x + bv.x;
    o.y = (v.y-mean)*rstd*wv.y + bv.y;
    o.z = (v.z-mean)*rstd*wv.z + bv.z;
    o.w = (v.w-mean)*rstd*wv.w + bv.w;
    ((float4*)(out + (size_t)row * D_))[tid] = o;
}

__global__ __launch_bounds__(256) void rope_kernel(float* __restrict__ qkv)
{
    int gid = blockIdx.x * 256 + threadIdx.x;
    int t = gid >> 9;
    int r = gid & 511;
    int h = r >> 5;
    int d = r & 31;
    // inv = 10000^(-d/32) = exp2(-d * log2(10000)/32); single v_exp_f32 vs powf
    float inv = exp2f((float)d * -0.4152410118609203f);
    float fr = (float)t * inv;
    float s, c;
    sincosf(fr, &s, &c);
    float* base = qkv + (size_t)t*D3_ + h*HD_ + d;
    float q1 = base[0], q2 = base[32];
    base[0]  = q1*c - q2*s;
    base[32] = q1*s + q2*c;
    float* kb = base + D_;
    float k1 = kb[0], k2 = kb[32];
    kb[0]  = k1*c - k2*s;
    kb[32] = k1*s + k2*c;
}

__global__ __launch_bounds__(256) void ln2_gate_kernel(
    const float* __restrict__ x2, const float* __restrict__ w,
    const float* __restrict__ b, const float* __restrict__ gwm,
    const float* __restrict__ gbv, float* __restrict__ h2,
    int* __restrict__ gi, float* __restrict__ gw)
{
    const int row = blockIdx.x, tid = threadIdx.x;
    const int lane = tid & 63, wave = tid >> 6;
    float4 v = ((const float4*)(x2 + (size_t)row * D_))[tid];
    float s  = v.x + v.y + v.z + v.w;
    float sq = v.x*v.x + v.y*v.y + v.z*v.z + v.w*v.w;
    #pragma unroll
    for (int off = 32; off; off >>= 1) {
        s  += __shfl_down(s, off);
        sq += __shfl_down(sq, off);
    }
    __shared__ float rs[4], rq[4], mv[2];
    if (lane == 0) { rs[wave] = s; rq[wave] = sq; }
    __syncthreads();
    if (tid == 0) {
        float ts = rs[0]+rs[1]+rs[2]+rs[3];
        float tq = rq[0]+rq[1]+rq[2]+rq[3];
        float mean = ts * (1.0f / D_);
        float var  = tq * (1.0f / D_) - mean*mean;
        mv[0] = mean; mv[1] = rsqrtf(var + 1e-5f);
    }
    __syncthreads();
    float mean = mv[0], rstd = mv[1];
    float4 wv = ((const float4*)w)[tid];
    float4 bv = ((const float4*)b)[tid];
    float hv[4];
    hv[0] = (v.x-mean)*rstd*wv.x + bv.x;
    hv[1] = (v.y-mean)*rstd*wv.y + bv.y;
    hv[2] = (v.z-mean)*rstd*wv.z + bv.z;
    hv[3] = (v.w-mean)*rstd*wv.w + bv.w;
    float4 o; o.x=hv[0]; o.y=hv[1]; o.z=hv[2]; o.w=hv[3];
    ((float4*)(h2 + (size_t)row * D_))[tid] = o;

    float acc[E_] = {};
    int c = tid * 4;
    #pragma unroll
    for (int j = 0; j < 4; j++) {
        const float* gr = gwm + (size_t)(c+j) * E_;
        #pragma unroll
        for (int e = 0; e < E_; e++) acc[e] += hv[j] * gr[e];
    }
    #pragma unroll
    for (int off = 32; off; off >>= 1)
        #pragma unroll
        for (int e = 0; e < E_; e++) acc[e] += __shfl_down(acc[e], off);
    __shared__ float gred[4][E_];
    if (lane == 0)
        for (int e = 0; e < E_; e++) gred[wave][e] = acc[e];
    __syncthreads();
    if (tid == 0) {
        float lg[E_];
        float mxl = -FLT_MAX; int mi = 0;
        for (int e = 0; e < E_; e++)
            lg[e] = gred[0][e]+gred[1][e]+gred[2][e]+gred[3][e] + gbv[e];
        for (int e = 0; e < E_; e++)
            if (lg[e] > mxl) { mxl = lg[e]; mi = e; }
        float ssum = 0.f;
        for (int e = 0; e < E_; e++) ssum += expf(lg[e] - mxl);
        gi[row] = mi;
        gw[row] = 1.0f / ssum;
    }
}

__global__ void route_kernel(const int* __restrict__ gi,
                             int* __restrict__ offs, int* __restrict__ perm)
{
    __shared__ int cnt[E_], c2[E_], off[E_+1];
    const int tid = threadIdx.x;
    if (tid < E_) { cnt[tid] = 0; c2[tid] = 0; }
    __syncthreads();
    int e = gi[tid];
    atomicAdd(&cnt[e], 1);
    __syncthreads();
    if (tid == 0) {
        off[0] = 0;
        for (int i = 0; i < E_; i++) off[i+1] = off[i] + cnt[i];
        for (int i = 0; i <= E_; i++) offs[i] = off[i];
    }
    __syncthreads();
    int r = atomicAdd(&c2[e], 1);
    perm[off[e] + r] = tid;
}

__global__ void loss_kernel(const int* __restrict__ gi,
                            const float* __restrict__ gw, float* __restrict__ out)
{
    __shared__ float ss[E_], sc[E_];
    const int tid = threadIdx.x;
    if (tid < E_) { ss[tid] = 0.f; sc[tid] = 0.f; }
    __syncthreads();
    for (int t = tid; t < T_; t += 256) {
        int e = gi[t];
        atomicAdd(&ss[e], gw[t]);
        atomicAdd(&sc[e], 1.0f);
    }
    __syncthreads();
    if (tid == 0) {
        float loss = 0.f;
        for (int e = 0; e < E_; e++) {
            float u = ss[e] / (sc[e] + 1e-8f);
            float d = u - 0.125f;
            loss += d * d;
        }
        out[(size_t)T_ * D_] = loss;
    }
}

extern "C" void kernel_launch(void* const* d_in, const int* in_sizes, int n_in,
                              void* d_out, int out_size, void* d_ws, size_t ws_size,
                              hipStream_t stream)
{
    const float* x     = (const float*)d_in[0];
    const int*   ids   = (const int*)d_in[1];
    const float* ln1w  = (const float*)d_in[2];
    const float* ln1b  = (const float*)d_in[3];
    const float* qkvw  = (const float*)d_in[4];
    const float* qkvb  = (const float*)d_in[5];
    const float* aow   = (const float*)d_in[6];
    const float* aob   = (const float*)d_in[7];
    const float* ln2w  = (const float*)d_in[8];
    const float* ln2b  = (const float*)d_in[9];
    const float* gatew = (const float*)d_in[10];
    const float* gateb = (const float*)d_in[11];
    const float* fcw   = (const float*)d_in[12];
    const float* fcb   = (const float*)d_in[13];
    const float* eoutw = (const float*)d_in[14];
    const float* eoutb = (const float*)d_in[15];
    float* out = (float*)d_out;
    float* ws  = (float*)d_ws;

    float* h    = ws + WS_H;      // reused as SACC after qkv GEMM
    float* sacc = ws + WS_H;
    float* qkv  = ws + WS_QKV;
    float* attn = ws + WS_ATTN;
    float* x2   = ws + WS_X2;
    float* h2   = ws + WS_H2;
    float* abuf = ws + WS_A;
    float* gw   = ws + WS_GW;
    int*   gi   = (int*)(ws + WS_GI);
    int*   offs = (int*)(ws + WS_OFFS);
    int*   perm = (int*)(ws + WS_PERM);

    // 1. LN1
    ln_kernel<<<T_, 256, 0, stream>>>(x, ln1w, ln1b, h);
    // 2. QKV projection (MFMA, pipelined)
    gemm_mfma_full<<<dim3(D3_/64, T_/128), 256, 0, stream>>>(
        h, D_, qkvw, D3_, qkvb, qkv, D3_, D_);
    // 3. RoPE
    rope_kernel<<<(T_*H_*32)/256, 256, 0, stream>>>(qkv);
    // 4. MFMA flash attention
    flash_attn<<<dim3(T_/32, H_), 128, 0, stream>>>(qkv, ids, attn);
    // 5. zero split-K accumulator
    hipMemsetAsync(sacc, 0, (size_t)T_*D_*sizeof(float), stream);
    // 6. attn output projection (MFMA, split-K=4)
    gemm_mfma_acc<<<dim3(D_/64, T_/128, 4), 256, 0, stream>>>(
        attn, D_, aow, D_, 0, nullptr, nullptr, sacc, D_, D_, 4);
    // 7. residual + bias
    ep_attn<<<T_, 256, 0, stream>>>(x, sacc, aob, x2);
    // 8. LN2 + gate
    ln2_gate_kernel<<<T_, 256, 0, stream>>>(x2, ln2w, ln2b, gatew, gateb, h2, gi, gw);
    // 9. routing
    route_kernel<<<1, T_, 0, stream>>>(gi, offs, perm);
    // 10. expert fc + GLU (MFMA, BN=32 pairs, pipelined)
    moe_fc_mfma<<<dim3(F_/32, T_/128, E_), 256, 0, stream>>>(h2, fcw, fcb, offs, perm, abuf);
    // 11. re-zero accumulator
    hipMemsetAsync(sacc, 0, (size_t)T_*D_*sizeof(float), stream);
    // 12. expert out (MFMA, split-K=4, routed)
    gemm_mfma_acc<<<dim3(D_/64, T_/128, 4*E_), 256, 0, stream>>>(
        abuf, F_, eoutw, D_, (long)F_*D_, offs, perm, sacc, D_, F_, 4);
    // 13. residual + gate scale + bias
    ep_moe<<<T_, 256, 0, stream>>>(x2, sacc, eoutb, gw, gi, out);
    // 14. aux loss
    loss_kernel<<<1, 256, 0, stream>>>(gi, gw, out);
}

// Round 3
// 548.275 us; speedup vs baseline: 1.0757x; 1.0757x over previous
//
#include <hip/hip_runtime.h>
#include <float.h>
#include <math.h>
#include <stdint.h>

#define T_ 1024
#define D_ 1024
#define H_ 16
#define HD_ 64
#define E_ 8
#define F_ 2560
#define D3_ 3072
#define F2_ 5120

// ---- workspace layout (float offsets) ----
// h/attn/h2/abuf are now bf16 (half the bytes) but keep the old slot sizes.
#define WS_H    0u         // LN1 out (bf16); later reused as SACC (fp32 split-K accum)
#define WS_QKV  1048576u   // 3M   qkv (T,3D) fp32
#define WS_ATTN 4194304u   // attention out (T,D) bf16
#define WS_X2   5242880u   // x + attn proj (T,D) fp32
#define WS_H2   6291456u   // LN2 out (T,D) bf16
#define WS_A    7340032u   // gated activation (T,F) bf16
#define WS_GW   9961472u
#define WS_GI   9962496u
#define WS_OFFS 9963520u
#define WS_PERM 9963536u

typedef short short8 __attribute__((ext_vector_type(8)));
typedef short short4v __attribute__((ext_vector_type(4)));
typedef __bf16 bf16x8 __attribute__((ext_vector_type(8)));
typedef float floatx4 __attribute__((ext_vector_type(4)));

union FragU { short8 s; bf16x8 b; };

__device__ __forceinline__ short f2bf(float f) {
    union { float f; uint32_t u; } a; a.f = f;
    uint32_t r = a.u + 0x7fffu + ((a.u >> 16) & 1u);
    return (short)(r >> 16);
}

__device__ __forceinline__ void cvt16(const float4& a0, const float4& a1,
                                      const float4& a2, const float4& a3,
                                      short8& c0, short8& c1) {
    c0[0]=f2bf(a0.x); c0[1]=f2bf(a0.y); c0[2]=f2bf(a0.z); c0[3]=f2bf(a0.w);
    c0[4]=f2bf(a1.x); c0[5]=f2bf(a1.y); c0[6]=f2bf(a1.z); c0[7]=f2bf(a1.w);
    c1[0]=f2bf(a2.x); c1[1]=f2bf(a2.y); c1[2]=f2bf(a2.z); c1[3]=f2bf(a2.w);
    c1[4]=f2bf(a3.x); c1[5]=f2bf(a3.y); c1[6]=f2bf(a3.z); c1[7]=f2bf(a3.w);
}

// ===================== MFMA GEMM cores =====================
// Tile: BM=128, BN=64, BK=32. 256 thr = 4 waves (2x2), wave tile 64x32.
// A operand is bf16 in global (pre-rounded by producers).
// K-loop unrolled x2 with two static register sets -> loads have ~2 sub-iters in flight.
#define GEMM_IDS \
    const int tid  = threadIdx.x;                 \
    const int a_m  = tid >> 1;                    \
    const int a_kh = (tid & 1) * 16;              \
    const int lane = tid & 63, wave = tid >> 6;   \
    const int wm = wave & 1,  wn = wave >> 1;     \
    const int quad = lane >> 4, lm = lane & 15;

__global__ __launch_bounds__(256) void gemm_mfma_full(
    const short* __restrict__ A, int lda,      // bf16 activations
    const float* __restrict__ B, int ldb,
    const float* __restrict__ bias,
    float* __restrict__ C, int ldc, int K)
{
    __shared__ __align__(16) short As[4*128*8];
    __shared__ __align__(16) short Bs[64*40];
    const int row0 = blockIdx.y * 128, col0 = blockIdx.x * 64;
    GEMM_IDS
    const int b_n = tid >> 2, b_kc = tid & 3;
    floatx4 acc[4][2];
    #pragma unroll
    for (int i=0;i<4;i++)
        #pragma unroll
        for (int j=0;j<2;j++) acc[i][j] = (floatx4){0.f,0.f,0.f,0.f};

    const short* apx = A + (size_t)(row0 + a_m) * lda + a_kh;
    const float* bpx = B + (size_t)(b_kc*8) * ldb + col0 + b_n;
    const int kcA = (tid & 1) * 2;

    short8 sA0, sA1, sB0, sB1;
    float bvA[8], bvB[8];
    sA0 = *(const short8*)(apx);
    sA1 = *(const short8*)(apx + 8);
    sB0 = *(const short8*)(apx + 32);
    sB1 = *(const short8*)(apx + 40);
    #pragma unroll
    for (int j=0;j<8;j++) bvA[j] = bpx[(size_t)j*ldb];
    {
        const float* bp2 = bpx + (size_t)32*ldb;
        #pragma unroll
        for (int j=0;j<8;j++) bvB[j] = bp2[(size_t)j*ldb];
    }

#define GF_STEP(S0,S1,BV,kpre)                                            \
    __syncthreads();                                                      \
    {                                                                     \
        short8 cb;                                                        \
        _Pragma("unroll")                                                 \
        for (int j=0;j<8;j++) cb[j] = f2bf(BV[j]);                        \
        *(short8*)&As[((kcA  )*128 + a_m)*8] = S0;                        \
        *(short8*)&As[((kcA+1)*128 + a_m)*8] = S1;                        \
        *(short8*)&Bs[b_n*40 + b_kc*8] = cb;                              \
    }                                                                     \
    __syncthreads();                                                      \
    if ((kpre) < K) {                                                     \
        S0 = *(const short8*)(apx + (kpre));                              \
        S1 = *(const short8*)(apx + (kpre) + 8);                          \
        const float* bp2 = bpx + (size_t)(kpre) * ldb;                    \
        _Pragma("unroll")                                                 \
        for (int j=0;j<8;j++) BV[j] = bp2[(size_t)j*ldb];                 \
    }                                                                     \
    {                                                                     \
        FragU fa[4], fb[2];                                               \
        _Pragma("unroll")                                                 \
        for (int i=0;i<4;i++) fa[i].s = *(short8*)&As[(quad*128 + wm*64 + i*16 + lm)*8]; \
        _Pragma("unroll")                                                 \
        for (int j=0;j<2;j++) fb[j].s = *(short8*)&Bs[(wn*32 + j*16 + lm)*40 + quad*8];  \
        _Pragma("unroll")                                                 \
        for (int i=0;i<4;i++)                                             \
            _Pragma("unroll")                                             \
            for (int j=0;j<2;j++)                                         \
                acc[i][j] = __builtin_amdgcn_mfma_f32_16x16x32_bf16(fa[i].b, fb[j].b, acc[i][j], 0,0,0); \
    }

    for (int k0 = 0; k0 < K; k0 += 64) {
        GF_STEP(sA0, sA1, bvA, k0 + 64)
        GF_STEP(sB0, sB1, bvB, k0 + 96)
    }
#undef GF_STEP

    #pragma unroll
    for (int i=0;i<4;i++)
        #pragma unroll
        for (int j=0;j<2;j++) {
            int col = col0 + wn*32 + j*16 + lm;
            float bb = bias ? bias[col] : 0.f;
            #pragma unroll
            for (int r=0;r<4;r++) {
                int row = row0 + wm*64 + i*16 + quad*4 + r;
                C[(size_t)row*ldc + col] = acc[i][j][r] + bb;
            }
        }
}

// split-K accumulating GEMM (optionally token-routed): Cacc += A@B
// blockIdx.y: sk = y % nsk, e = y / nsk.  blockIdx.z = row block (mostly-dead dim last!)
__global__ __launch_bounds__(256) void gemm_mfma_acc(
    const short* __restrict__ A, int lda,      // bf16 activations
    const float* __restrict__ B, int ldb, long sB,
    const int* __restrict__ offs, const int* __restrict__ perm,
    float* __restrict__ Cacc, int ldc, int K, int nsk)
{
    const int sk = blockIdx.y % nsk;
    const int e  = blockIdx.y / nsk;
    int off = 0, Ne = T_;
    if (offs) { off = offs[e]; Ne = offs[e+1] - off; }
    const int row0 = blockIdx.z * 128;
    if (row0 >= Ne) return;
    const int col0 = blockIdx.x * 64;
    B += (long)e * sB;

    __shared__ __align__(16) short As[4*128*8];
    __shared__ __align__(16) short Bs[64*40];
    __shared__ int toks[128];
    GEMM_IDS
    const int b_n = tid >> 2, b_kc = tid & 3;
    if (tid < 128) {
        int r = row0 + tid;
        toks[tid] = offs ? ((r < Ne) ? perm[off + r] : -1) : r;
    }
    __syncthreads();

    floatx4 acc[4][2];
    #pragma unroll
    for (int i=0;i<4;i++)
        #pragma unroll
        for (int j=0;j<2;j++) acc[i][j] = (floatx4){0.f,0.f,0.f,0.f};

    const int tokA = toks[a_m];
    const short* apx = (tokA >= 0) ? (A + (size_t)tokA * lda + a_kh) : nullptr;
    const float* bpx = B + (size_t)(b_kc*8) * ldb + col0 + b_n;
    const int kcA = (tid & 1) * 2;
    const int Kp = K / nsk;
    const int koff = sk * Kp, kend = koff + Kp;

    short8 sA0 = {0,0,0,0,0,0,0,0}, sA1 = sA0, sB0 = sA0, sB1 = sA0;
    float bvA[8], bvB[8];
    if (apx) {
        sA0 = *(const short8*)(apx + koff);
        sA1 = *(const short8*)(apx + koff + 8);
        sB0 = *(const short8*)(apx + koff + 32);
        sB1 = *(const short8*)(apx + koff + 40);
    }
    {
        const float* bp2 = bpx + (size_t)koff * ldb;
        #pragma unroll
        for (int j=0;j<8;j++) bvA[j] = bp2[(size_t)j*ldb];
        bp2 += (size_t)32 * ldb;
        #pragma unroll
        for (int j=0;j<8;j++) bvB[j] = bp2[(size_t)j*ldb];
    }

#define GA_STEP(S0,S1,BV,kpre)                                            \
    __syncthreads();                                                      \
    {                                                                     \
        short8 cb;                                                        \
        _Pragma("unroll")                                                 \
        for (int j=0;j<8;j++) cb[j] = f2bf(BV[j]);                        \
        *(short8*)&As[((kcA  )*128 + a_m)*8] = S0;                        \
        *(short8*)&As[((kcA+1)*128 + a_m)*8] = S1;                        \
        *(short8*)&Bs[b_n*40 + b_kc*8] = cb;                              \
    }                                                                     \
    __syncthreads();                                                      \
    if ((kpre) < kend) {                                                  \
        if (apx) {                                                        \
            S0 = *(const short8*)(apx + (kpre));                          \
            S1 = *(const short8*)(apx + (kpre) + 8);                      \
        }                                                                 \
        const float* bp2 = bpx + (size_t)(kpre) * ldb;                    \
        _Pragma("unroll")                                                 \
        for (int j=0;j<8;j++) BV[j] = bp2[(size_t)j*ldb];                 \
    }                                                                     \
    {                                                                     \
        FragU fa[4], fb[2];                                               \
        _Pragma("unroll")                                                 \
        for (int i=0;i<4;i++) fa[i].s = *(short8*)&As[(quad*128 + wm*64 + i*16 + lm)*8]; \
        _Pragma("unroll")                                                 \
        for (int j=0;j<2;j++) fb[j].s = *(short8*)&Bs[(wn*32 + j*16 + lm)*40 + quad*8];  \
        _Pragma("unroll")                                                 \
        for (int i=0;i<4;i++)                                             \
            _Pragma("unroll")                                             \
            for (int j=0;j<2;j++)                                         \
                acc[i][j] = __builtin_amdgcn_mfma_f32_16x16x32_bf16(fa[i].b, fb[j].b, acc[i][j], 0,0,0); \
    }

    for (int k0 = koff; k0 < kend; k0 += 64) {
        GA_STEP(sA0, sA1, bvA, k0 + 64)
        GA_STEP(sB0, sB1, bvB, k0 + 96)
    }
#undef GA_STEP

    #pragma unroll
    for (int i=0;i<4;i++)
        #pragma unroll
        for (int j=0;j<2;j++) {
            int col = col0 + wn*32 + j*16 + lm;
            #pragma unroll
            for (int r=0;r<4;r++) {
                int tk = toks[wm*64 + i*16 + quad*4 + r];
                if (tk >= 0) atomicAdd(&Cacc[(size_t)tk*ldc + col], acc[i][j][r]);
            }
        }
}

// MoE fc: BN=32-col pair (x1 col c, x2 col F_+c), wave tile 64x16, GLU epilogue (bf16 out).
// blockIdx.y = expert, blockIdx.z = row block (mostly dead -> last).
__global__ __launch_bounds__(256) void moe_fc_mfma(
    const short* __restrict__ h2, const float* __restrict__ fcw,
    const float* __restrict__ fcb, const int* __restrict__ offs,
    const int* __restrict__ perm, short* __restrict__ aout)
{
    const int e = blockIdx.y;
    const int off = offs[e];
    const int Ne = offs[e+1] - off;
    const int row0 = blockIdx.z * 128;
    if (row0 >= Ne) return;
    const int col0 = blockIdx.x * 32;

    __shared__ __align__(16) short As[4*128*8];
    __shared__ __align__(16) short B1s[32*40];
    __shared__ __align__(16) short B2s[32*40];
    __shared__ int toks[128];
    GEMM_IDS
    const int n_l = tid & 31, kg = tid >> 5;   // B: col n_l, k-rows kg*4..+3
    if (tid < 128) {
        int r = row0 + tid;
        toks[tid] = (r < Ne) ? perm[off + r] : -1;
    }
    __syncthreads();

    floatx4 acc1[4], acc2[4];
    #pragma unroll
    for (int i=0;i<4;i++) {
        acc1[i] = (floatx4){0.f,0.f,0.f,0.f};
        acc2[i] = (floatx4){0.f,0.f,0.f,0.f};
    }

    const float* W = fcw + (size_t)e * D_ * F2_;
    const int tokA = toks[a_m];
    const short* apx = (tokA >= 0) ? (h2 + (size_t)tokA * D_ + a_kh) : nullptr;
    const float* bpx = W + (size_t)(kg*4) * F2_ + col0 + n_l;
    const int kcA = (tid & 1) * 2;

    short8 sA0 = {0,0,0,0,0,0,0,0}, sA1 = sA0, sB0 = sA0, sB1 = sA0;
    float b1A[4], b2A[4], b1B[4], b2B[4];
    if (apx) {
        sA0 = *(const short8*)(apx);
        sA1 = *(const short8*)(apx + 8);
        sB0 = *(const short8*)(apx + 32);
        sB1 = *(const short8*)(apx + 40);
    }
    #pragma unroll
    for (int j=0;j<4;j++) { b1A[j] = bpx[(size_t)j*F2_]; b2A[j] = bpx[(size_t)j*F2_ + F_]; }
    {
        const float* bp2 = bpx + (size_t)32*F2_;
        #pragma unroll
        for (int j=0;j<4;j++) { b1B[j] = bp2[(size_t)j*F2_]; b2B[j] = bp2[(size_t)j*F2_ + F_]; }
    }

#define MF_STEP(S0,S1,BV1,BV2,kpre)                                       \
    __syncthreads();                                                      \
    {                                                                     \
        short4v cb1, cb2;                                                 \
        _Pragma("unroll")                                                 \
        for (int j=0;j<4;j++) { cb1[j] = f2bf(BV1[j]); cb2[j] = f2bf(BV2[j]); } \
        *(short8*)&As[((kcA  )*128 + a_m)*8] = S0;                        \
        *(short8*)&As[((kcA+1)*128 + a_m)*8] = S1;                        \
        *(short4v*)&B1s[n_l*40 + kg*4] = cb1;                             \
        *(short4v*)&B2s[n_l*40 + kg*4] = cb2;                             \
    }                                                                     \
    __syncthreads();                                                      \
    if ((kpre) < D_) {                                                    \
        if (apx) {                                                        \
            S0 = *(const short8*)(apx + (kpre));                          \
            S1 = *(const short8*)(apx + (kpre) + 8);                      \
        }                                                                 \
        const float* bp2 = bpx + (size_t)(kpre) * F2_;                    \
        _Pragma("unroll")                                                 \
        for (int j=0;j<4;j++) { BV1[j] = bp2[(size_t)j*F2_]; BV2[j] = bp2[(size_t)j*F2_ + F_]; } \
    }                                                                     \
    {                                                                     \
        FragU fa[4], fb1, fb2;                                            \
        _Pragma("unroll")                                                 \
        for (int i=0;i<4;i++) fa[i].s = *(short8*)&As[(quad*128 + wm*64 + i*16 + lm)*8]; \
        fb1.s = *(short8*)&B1s[(wn*16 + lm)*40 + quad*8];                 \
        fb2.s = *(short8*)&B2s[(wn*16 + lm)*40 + quad*8];                 \
        _Pragma("unroll")                                                 \
        for (int i=0;i<4;i++) {                                           \
            acc1[i] = __builtin_amdgcn_mfma_f32_16x16x32_bf16(fa[i].b, fb1.b, acc1[i], 0,0,0); \
            acc2[i] = __builtin_amdgcn_mfma_f32_16x16x32_bf16(fa[i].b, fb2.b, acc2[i], 0,0,0); \
        }                                                                 \
    }

    for (int k0 = 0; k0 < D_; k0 += 64) {
        MF_STEP(sA0, sA1, b1A, b2A, k0 + 64)
        MF_STEP(sB0, sB1, b1B, b2B, k0 + 96)
    }
#undef MF_STEP

    {
        int col = col0 + wn*16 + lm;
        float b1 = fcb[(size_t)e*F2_ + col];
        float b2 = fcb[(size_t)e*F2_ + F_ + col];
        #pragma unroll
        for (int i=0;i<4;i++)
            #pragma unroll
            for (int r=0;r<4;r++) {
                int tk = toks[wm*64 + i*16 + quad*4 + r];
                if (tk < 0) continue;
                float v1 = acc1[i][r] + b1;
                float v2 = acc2[i][r] + b2;
                float g = v2 * 0.5f * (1.0f + erff(v2 * 0.70710678118654752f));
                aout[(size_t)tk*F_ + col] = f2bf(v1 * g);
            }
    }
}

// ===================== MFMA flash attention =====================
__global__ __launch_bounds__(128) void flash_attn(
    const float* __restrict__ qkv, const int* __restrict__ ids,
    short* __restrict__ attnout)
{
    const int h  = blockIdx.y;
    const int q0 = blockIdx.x * 32;
    const int tid = threadIdx.x;
    const int lane = tid & 63, w = tid >> 6;
    const int quad = lane >> 4, lm = lane & 15;

    __shared__ __align__(16) short Qs[32*72];
    __shared__ __align__(16) short Ks[64*72];
    __shared__ __align__(16) short Vt[64*72];
    __shared__ __align__(16) short Ps[2][16*72];
    __shared__ int globf[32];

    {
        int row = tid >> 2, c = (tid & 3) * 16;
        const float* qp = qkv + (size_t)(q0 + row) * D3_ + h * HD_ + c;
        float4 f0 = *(const float4*)(qp);
        float4 f1 = *(const float4*)(qp + 4);
        float4 f2 = *(const float4*)(qp + 8);
        float4 f3 = *(const float4*)(qp + 12);
        short8 s0, s1;
        cvt16(f0, f1, f2, f3, s0, s1);
        *(short8*)&Qs[row*72 + c]     = s0;
        *(short8*)&Qs[row*72 + c + 8] = s1;
    }
    if (tid < 32) {
        int id = ids[q0 + tid];
        globf[tid] = (id >= 2 && id <= 7) ? 1 : 0;
    }
    __syncthreads();

    FragU QA[2];
    #pragma unroll
    for (int s = 0; s < 2; s++)
        QA[s].s = *(short8*)&Qs[(w*16 + lm)*72 + s*32 + quad*8];

    int any = 0;
    #pragma unroll
    for (int i = 0; i < 32; i++) any |= globf[i];
    const int nt = any ? (T_/64) : ((q0 + 31) >> 6) + 1;

    int gq[4]; int qidx[4];
    #pragma unroll
    for (int r = 0; r < 4; r++) {
        int ql = w*16 + quad*4 + r;
        qidx[r] = q0 + ql;
        gq[r] = globf[ql];
    }

    float mrow[4] = {-1e30f, -1e30f, -1e30f, -1e30f};
    float lrow[4] = {0.f, 0.f, 0.f, 0.f};
    floatx4 Oacc[4];
    #pragma unroll
    for (int n = 0; n < 4; n++) Oacc[n] = (floatx4){0.f, 0.f, 0.f, 0.f};

    for (int kt = 0; kt < nt; kt++) {
        __syncthreads();
        #pragma unroll
        for (int rep = 0; rep < 2; rep++) {
            int key = (tid >> 2) + rep*32;
            int c = (tid & 3) * 16;
            const float* kp = qkv + (size_t)(kt*64 + key) * D3_ + D_ + h*HD_ + c;
            float4 f0 = *(const float4*)(kp);
            float4 f1 = *(const float4*)(kp + 4);
            float4 f2 = *(const float4*)(kp + 8);
            float4 f3 = *(const float4*)(kp + 12);
            short8 s0, s1;
            cvt16(f0, f1, f2, f3, s0, s1);
            *(short8*)&Ks[key*72 + c]     = s0;
            *(short8*)&Ks[key*72 + c + 8] = s1;
        }
        #pragma unroll
        for (int rep = 0; rep < 8; rep++) {
            int lin = tid + rep*128;
            int key = lin >> 4;
            int c = (lin & 15) * 4;
            const float* vp = qkv + (size_t)(kt*64 + key) * D3_ + 2*D_ + h*HD_ + c;
            float4 f = *(const float4*)vp;
            Vt[(c+0)*72 + key] = f2bf(f.x);
            Vt[(c+1)*72 + key] = f2bf(f.y);
            Vt[(c+2)*72 + key] = f2bf(f.z);
            Vt[(c+3)*72 + key] = f2bf(f.w);
        }
        __syncthreads();

        floatx4 Sv[4];
        #pragma unroll
        for (int n = 0; n < 4; n++) {
            Sv[n] = (floatx4){0.f, 0.f, 0.f, 0.f};
            #pragma unroll
            for (int s = 0; s < 2; s++) {
                FragU KB;
                KB.s = *(short8*)&Ks[(n*16 + lm)*72 + s*32 + quad*8];
                Sv[n] = __builtin_amdgcn_mfma_f32_16x16x32_bf16(QA[s].b, KB.b, Sv[n], 0, 0, 0);
            }
        }
        #pragma unroll
        for (int n = 0; n < 4; n++) {
            int key = kt*64 + n*16 + lm;
            #pragma unroll
            for (int r = 0; r < 4; r++) {
                float v = Sv[n][r] * 0.125f;
                if (!gq[r] && key > qidx[r]) v = -1e30f;
                Sv[n][r] = v;
            }
        }
        float mnew[4], alpha[4], tsum[4];
        #pragma unroll
        for (int r = 0; r < 4; r++) {
            float tm = fmaxf(fmaxf(Sv[0][r], Sv[1][r]), fmaxf(Sv[2][r], Sv[3][r]));
            #pragma unroll
            for (int x = 1; x < 16; x <<= 1) tm = fmaxf(tm, __shfl_xor(tm, x));
            mnew[r] = fmaxf(mrow[r], tm);
            alpha[r] = __expf(mrow[r] - mnew[r]);
            mrow[r] = mnew[r];
            tsum[r] = 0.f;
        }
        #pragma unroll
        for (int n = 0; n < 4; n++) {
            #pragma unroll
            for (int r = 0; r < 4; r++) {
                float p = __expf(Sv[n][r] - mnew[r]);
                tsum[r] += p;
                Ps[w][(quad*4 + r)*72 + n*16 + lm] = f2bf(p);
            }
        }
        #pragma unroll
        for (int r = 0; r < 4; r++) {
            #pragma unroll
            for (int x = 1; x < 16; x <<= 1) tsum[r] += __shfl_xor(tsum[r], x);
            lrow[r] = lrow[r] * alpha[r] + tsum[r];
        }
        #pragma unroll
        for (int n = 0; n < 4; n++)
            #pragma unroll
            for (int r = 0; r < 4; r++) Oacc[n][r] *= alpha[r];

        #pragma unroll
        for (int s = 0; s < 2; s++) {
            FragU PA;
            PA.s = *(short8*)&Ps[w][lm*72 + s*32 + quad*8];
            #pragma unroll
            for (int n = 0; n < 4; n++) {
                FragU VB;
                VB.s = *(short8*)&Vt[(n*16 + lm)*72 + s*32 + quad*8];
                Oacc[n] = __builtin_amdgcn_mfma_f32_16x16x32_bf16(PA.b, VB.b, Oacc[n], 0, 0, 0);
            }
        }
    }

    #pragma unroll
    for (int n = 0; n < 4; n++)
        #pragma unroll
        for (int r = 0; r < 4; r++) {
            float o = Oacc[n][r] / lrow[r];
            attnout[(size_t)qidx[r]*D_ + h*HD_ + n*16 + lm] = f2bf(o);
        }
}

// ===================== epilogues =====================
__global__ __launch_bounds__(256) void ep_attn(
    const float* __restrict__ x, const float* __restrict__ sacc,
    const float* __restrict__ aob, float* __restrict__ x2)
{
    int row = blockIdx.x, tid = threadIdx.x;
    float4 xv = ((const float4*)(x + (size_t)row*D_))[tid];
    float4 sv = ((const float4*)(sacc + (size_t)row*D_))[tid];
    float4 bv = ((const float4*)aob)[tid];
    float4 o;
    o.x = xv.x + sv.x + bv.x; o.y = xv.y + sv.y + bv.y;
    o.z = xv.z + sv.z + bv.z; o.w = xv.w + sv.w + bv.w;
    ((float4*)(x2 + (size_t)row*D_))[tid] = o;
}

__global__ __launch_bounds__(256) void ep_moe(
    const float* __restrict__ x2, const float* __restrict__ sacc,
    const float* __restrict__ eob, const float* __restrict__ gw,
    const int* __restrict__ gi, float* __restrict__ out)
{
    int row = blockIdx.x, tid = threadIdx.x;
    float g = gw[row];
    int e = gi[row];
    float4 xv = ((const float4*)(x2 + (size_t)row*D_))[tid];
    float4 sv = ((const float4*)(sacc + (size_t)row*D_))[tid];
    float4 bv = ((const float4*)(eob + (size_t)e*D_))[tid];
    float4 o;
    o.x = xv.x + g*(sv.x + bv.x); o.y = xv.y + g*(sv.y + bv.y);
    o.z = xv.z + g*(sv.z + bv.z); o.w = xv.w + g*(sv.w + bv.w);
    ((float4*)(out + (size_t)row*D_))[tid] = o;
}

// ===================== small kernels =====================
__global__ __launch_bounds__(256) void ln_kernel(
    const float* __restrict__ x, const float* __restrict__ w,
    const float* __restrict__ b, short* __restrict__ out)   // bf16 out
{
    const int row = blockIdx.x, tid = threadIdx.x;
    const int lane = tid & 63, wave = tid >> 6;
    float4 v = ((const float4*)(x + (size_t)row * D_))[tid];
    float s  = v.x + v.y + v.z + v.w;
    float sq = v.x*v.x + v.y*v.y + v.z*v.z + v.w*v.w;
    #pragma unroll
    for (int off = 32; off; off >>= 1) {
        s  += __shfl_down(s, off);
        sq += __shfl_down(sq, off);
    }
    __shared__ float rs[4], rq[4], mv[2];
    if (lane == 0) { rs[wave] = s; rq[wave] = sq; }
    __syncthreads();
    if (tid == 0) {
        float ts = rs[0]+rs[1]+rs[2]+rs[3];
        float tq = rq[0]+rq[1]+rq[2]+rq[3];
        float mean = ts * (1.0f / D_);
        float var  = tq * (1.0f / D_) - mean*mean;
        mv[0] = mean; mv[1] = rsqrtf(var + 1e-5f);
    }
    __syncthreads();
    float mean = mv[0], rstd = mv[1];
    float4 wv = ((const float4*)w)[tid];
    float4 bv = ((const float4*)b)[tid];
    short4v o;
    o[0] = f2bf((v.x-mean)*rstd*wv.x + bv.x);
    o[1] = f2bf((v.y-mean)*rstd*wv.y + bv.y);
    o[2] = f2bf((v.z-mean)*rstd*wv.z + bv.z);
    o[3] = f2bf((v.w-mean)*rstd*wv.w + bv.w);
    ((short4v*)(out + (size_t)row * D_))[tid] = o;
}

__global__ __launch_bounds__(256) void rope_kernel(float* __restrict__ qkv)
{
    int gid = blockIdx.x * 256 + threadIdx.x;
    int t = gid >> 9;
    int r = gid & 511;
    int h = r >> 5;
    int d = r & 31;
    float inv = exp2f((float)d * -0.4152410118609203f);
    float fr = (float)t * inv;
    float s, c;
    sincosf(fr, &s, &c);
    float* base = qkv + (size_t)t*D3_ + h*HD_ + d;
    float q1 = base[0], q2 = base[32];
    base[0]  = q1*c - q2*s;
    base[32] = q1*s + q2*c;
    float* kb = base + D_;
    float k1 = kb[0], k2 = kb[32];
    kb[0]  = k1*c - k2*s;
    kb[32] = k1*s + k2*c;
}

__global__ __launch_bounds__(256) void ln2_gate_kernel(
    const float* __restrict__ x2, const float* __restrict__ w,
    const float* __restrict__ b, const float* __restrict__ gwm,
    const float* __restrict__ gbv, short* __restrict__ h2,   // bf16 out
    int* __restrict__ gi, float* __restrict__ gw)
{
    const int row = blockIdx.x, tid = threadIdx.x;
    const int lane = tid & 63, wave = tid >> 6;
    float4 v = ((const float4*)(x2 + (size_t)row * D_))[tid];
    float s  = v.x + v.y + v.z + v.w;
    float sq = v.x*v.x + v.y*v.y + v.z*v.z + v.w*v.w;
    #pragma unroll
    for (int off = 32; off; off >>= 1) {
        s  += __shfl_down(s, off);
        sq += __shfl_down(sq, off);
    }
    __shared__ float rs[4], rq[4], mv[2];
    if (lane == 0) { rs[wave] = s; rq[wave] = sq; }
    __syncthreads();
    if (tid == 0) {
        float ts = rs[0]+rs[1]+rs[2]+rs[3];
        float tq = rq[0]+rq[1]+rq[2]+rq[3];
        float mean = ts * (1.0f / D_);
        float var  = tq * (1.0f / D_) - mean*mean;
        mv[0] = mean; mv[1] = rsqrtf(var + 1e-5f);
    }
    __syncthreads();
    float mean = mv[0], rstd = mv[1];
    float4 wv = ((const float4*)w)[tid];
    float4 bv = ((const float4*)b)[tid];
    float hv[4];
    hv[0] = (v.x-mean)*rstd*wv.x + bv.x;
    hv[1] = (v.y-mean)*rstd*wv.y + bv.y;
    hv[2] = (v.z-mean)*rstd*wv.z + bv.z;
    hv[3] = (v.w-mean)*rstd*wv.w + bv.w;
    short4v o;
    o[0]=f2bf(hv[0]); o[1]=f2bf(hv[1]); o[2]=f2bf(hv[2]); o[3]=f2bf(hv[3]);
    ((short4v*)(h2 + (size_t)row * D_))[tid] = o;

    float acc[E_] = {};
    int c = tid * 4;
    #pragma unroll
    for (int j = 0; j < 4; j++) {
        const float* gr = gwm + (size_t)(c+j) * E_;
        #pragma unroll
        for (int e = 0; e < E_; e++) acc[e] += hv[j] * gr[e];
    }
    #pragma unroll
    for (int off = 32; off; off >>= 1)
        #pragma unroll
        for (int e = 0; e < E_; e++) acc[e] += __shfl_down(acc[e], off);
    __shared__ float gred[4][E_];
    if (lane == 0)
        for (int e = 0; e < E_; e++) gred[wave][e] = acc[e];
    __syncthreads();
    if (tid == 0) {
        float lg[E_];
        float mxl = -FLT_MAX; int mi = 0;
        for (int e = 0; e < E_; e++)
            lg[e] = gred[0][e]+gred[1][e]+gred[2][e]+gred[3][e] + gbv[e];
        for (int e = 0; e < E_; e++)
            if (lg[e] > mxl) { mxl = lg[e]; mi = e; }
        float ssum = 0.f;
        for (int e = 0; e < E_; e++) ssum += expf(lg[e] - mxl);
        gi[row] = mi;
        gw[row] = 1.0f / ssum;
    }
}

__global__ void route_kernel(const int* __restrict__ gi,
                             int* __restrict__ offs, int* __restrict__ perm)
{
    __shared__ int cnt[E_], c2[E_], off[E_+1];
    const int tid = threadIdx.x;
    if (tid < E_) { cnt[tid] = 0; c2[tid] = 0; }
    __syncthreads();
    int e = gi[tid];
    atomicAdd(&cnt[e], 1);
    __syncthreads();
    if (tid == 0) {
        off[0] = 0;
        for (int i = 0; i < E_; i++) off[i+1] = off[i] + cnt[i];
        for (int i = 0; i <= E_; i++) offs[i] = off[i];
    }
    __syncthreads();
    int r = atomicAdd(&c2[e], 1);
    perm[off[e] + r] = tid;
}

__global__ void loss_kernel(const int* __restrict__ gi,
                            const float* __restrict__ gw, float* __restrict__ out)
{
    __shared__ float ss[E_], sc[E_];
    const int tid = threadIdx.x;
    if (tid < E_) { ss[tid] = 0.f; sc[tid] = 0.f; }
    __syncthreads();
    for (int t = tid; t < T_; t += 256) {
        int e = gi[t];
        atomicAdd(&ss[e], gw[t]);
        atomicAdd(&sc[e], 1.0f);
    }
    __syncthreads();
    if (tid == 0) {
        float loss = 0.f;
        for (int e = 0; e < E_; e++) {
            float u = ss[e] / (sc[e] + 1e-8f);
            float d = u - 0.125f;
            loss += d * d;
        }
        out[(size_t)T_ * D_] = loss;
    }
}

extern "C" void kernel_launch(void* const* d_in, const int* in_sizes, int n_in,
                              void* d_out, int out_size, void* d_ws, size_t ws_size,
                              hipStream_t stream)
{
    const float* x     = (const float*)d_in[0];
    const int*   ids   = (const int*)d_in[1];
    const float* ln1w  = (const float*)d_in[2];
    const float* ln1b  = (const float*)d_in[3];
    const float* qkvw  = (const float*)d_in[4];
    const float* qkvb  = (const float*)d_in[5];
    const float* aow   = (const float*)d_in[6];
    const float* aob   = (const float*)d_in[7];
    const float* ln2w  = (const float*)d_in[8];
    const float* ln2b  = (const float*)d_in[9];
    const float* gatew = (const float*)d_in[10];
    const float* gateb = (const float*)d_in[11];
    const float* fcw   = (const float*)d_in[12];
    const float* fcb   = (const float*)d_in[13];
    const float* eoutw = (const float*)d_in[14];
    const float* eoutb = (const float*)d_in[15];
    float* out = (float*)d_out;
    float* ws  = (float*)d_ws;

    short* hb    = (short*)(ws + WS_H);   // bf16 LN1 out; slot reused as SACC later
    float* sacc  = ws + WS_H;
    float* qkv   = ws + WS_QKV;
    short* attnb = (short*)(ws + WS_ATTN);
    float* x2    = ws + WS_X2;
    short* h2b   = (short*)(ws + WS_H2);
    short* abuf  = (short*)(ws + WS_A);
    float* gw    = ws + WS_GW;
    int*   gi    = (int*)(ws + WS_GI);
    int*   offs  = (int*)(ws + WS_OFFS);
    int*   perm  = (int*)(ws + WS_PERM);

    // 1. LN1 (bf16 out)
    ln_kernel<<<T_, 256, 0, stream>>>(x, ln1w, ln1b, hb);
    // 2. QKV projection
    gemm_mfma_full<<<dim3(D3_/64, T_/128), 256, 0, stream>>>(
        hb, D_, qkvw, D3_, qkvb, qkv, D3_, D_);
    // 3. RoPE
    rope_kernel<<<(T_*H_*32)/256, 256, 0, stream>>>(qkv);
    // 4. MFMA flash attention (bf16 out)
    flash_attn<<<dim3(T_/32, H_), 128, 0, stream>>>(qkv, ids, attnb);
    // 5. zero split-K accumulator
    hipMemsetAsync(sacc, 0, (size_t)T_*D_*sizeof(float), stream);
    // 6. attn output projection (split-K=4); y=(sk,e), z=row blocks
    gemm_mfma_acc<<<dim3(D_/64, 4, T_/128), 256, 0, stream>>>(
        attnb, D_, aow, D_, 0, nullptr, nullptr, sacc, D_, D_, 4);
    // 7. residual + bias
    ep_attn<<<T_, 256, 0, stream>>>(x, sacc, aob, x2);
    // 8. LN2 + gate (bf16 h2)
    ln2_gate_kernel<<<T_, 256, 0, stream>>>(x2, ln2w, ln2b, gatew, gateb, h2b, gi, gw);
    // 9. routing
    route_kernel<<<1, T_, 0, stream>>>(gi, offs, perm);
    // 10. expert fc + GLU; y=expert, z=row blocks (mostly dead -> dispatched last)
    moe_fc_mfma<<<dim3(F_/32, E_, T_/128), 256, 0, stream>>>(h2b, fcw, fcb, offs, perm, abuf);
    // 11. re-zero accumulator
    hipMemsetAsync(sacc, 0, (size_t)T_*D_*sizeof(float), stream);
    // 12. expert out (split-K=4, routed); y=(sk,e), z=row blocks
    gemm_mfma_acc<<<dim3(D_/64, 4*E_, T_/128), 256, 0, stream>>>(
        abuf, F_, eoutw, D_, (long)F_*D_, offs, perm, sacc, D_, F_, 4);
    // 13. residual + gate scale + bias
    ep_moe<<<T_, 256, 0, stream>>>(x2, sacc, eoutb, gw, gi, out);
    // 14. aux loss
    loss_kernel<<<1, 256, 0, stream>>>(gi, gw, out);
}